// Round 9
// baseline (1009.646 us; speedup 1.0000x reference)
//
#include <hip/hip_runtime.h>
#include <stdint.h>

#define FEAT_STRIDE_I 16
#define A_NUM 9
#define HH 128
#define WW 128
#define NPIX (HH * WW)            // 16384
#define N_ANCH (NPIX * A_NUM)     // 147456
#define B_NUM 8
#define PRE_NMS 6000
#define POST_NMS 300
#define NMS_THRESH_F 0.7f
#define MIN_SIZE_F 16.0f
#define NEG_INF_F -1e30f
#define NB2 32768                  // 15-bit bins (key>>17)
#define SEGCAP 16384

#define RT_TILES 94                // ceil(6000/64)
#define GT_TILES 600               // sum_R ceil((94-R)/8): 8-column groups
#define BQWORDS (RT_TILES * RT_TILES * 64)   // 565,504 qwords per batch
#define CHUNKQ (RT_TILES * 64)     // 6016 qwords per row-tile chunk
#define SCAN_STRIDE 95             // LDS row padding (2-way bank max)

// swizzled LDS index: chunk walks (stride 32) become conflict-free
#define SW(i) ((i) + ((i) >> 5))

// ---- workspace layout (bytes) ----
#define OFF_BINCNT  0u             // 8*32768*4 = 1,048,576 (zeroed)
#define OFF_CNT     1048576u       // cnt[8] + thresh[8] (512 B)
#define OFF_BINBASE 1049088u       // 1,048,576
#define OFF_HISTG   2097664u       // 1,048,576
#define OFF_SEG     3146240u       // 8*16384*8 = 1,048,576
#define OFF_KEYS    4194816u       // 8*147456*4 = 4,718,592
#define OFF_BOXES   8913408u       // 8*6000*4*4 = 768,000
#define OFF_KEPT    9681408u       // 8*304*4 = 9,728
#define OFF_MASK    9691136u       // 8*565504*8 = 36,192,256 -> end 45,883,392
#define MASK_BYTES ((size_t)B_NUM * BQWORDS * 8)

__device__ __forceinline__ unsigned sortable_f32(float f) {
    unsigned u = __float_as_uint(f);
    return (u & 0x80000000u) ? ~u : (u | 0x80000000u);
}

// Decode one anchor's box exactly in the reference's op order.
__device__ __forceinline__ void decode_box(
    int b, int idx,
    const float* __restrict__ deltas, const float* __restrict__ im_info,
    const float* __restrict__ anchors,
    float& x1, float& y1, float& x2, float& y2, bool& valid)
{
    int a   = idx % A_NUM;
    int pix = idx / A_NUM;
    int w   = pix & (WW - 1);
    int h   = pix >> 7;

    float a0 = anchors[a * 4 + 0];
    float a1 = anchors[a * 4 + 1];
    float a2 = anchors[a * 4 + 2];
    float a3 = anchors[a * 4 + 3];

    float aw = __fadd_rn(__fsub_rn(a2, a0), 1.0f);
    float ah = __fadd_rn(__fsub_rn(a3, a1), 1.0f);
    float sx = (float)(w * FEAT_STRIDE_I);
    float sy = (float)(h * FEAT_STRIDE_I);
    float acx = __fadd_rn(__fadd_rn(sx, a0), __fmul_rn(0.5f, aw));
    float acy = __fadd_rn(__fadd_rn(sy, a1), __fmul_rn(0.5f, ah));

    size_t base = ((size_t)b * 36 + 4 * a) * NPIX + pix;
    float dx = deltas[base];
    float dy = deltas[base + NPIX];
    float dw = deltas[base + 2 * (size_t)NPIX];
    float dh = deltas[base + 3 * (size_t)NPIX];

    float pcx = __fadd_rn(__fmul_rn(dx, aw), acx);
    float pcy = __fadd_rn(__fmul_rn(dy, ah), acy);
    float pw  = __fmul_rn(expf(dw), aw);
    float ph  = __fmul_rn(expf(dh), ah);

    float hx = __fmul_rn(0.5f, pw);
    float hy = __fmul_rn(0.5f, ph);
    x1 = __fsub_rn(pcx, hx);
    y1 = __fsub_rn(pcy, hy);
    x2 = __fadd_rn(pcx, hx);
    y2 = __fadd_rn(pcy, hy);

    float im_h = im_info[b * 3 + 0];
    float im_w = im_info[b * 3 + 1];
    float sc   = im_info[b * 3 + 2];
    float wmax = __fsub_rn(im_w, 1.0f);
    float hmax = __fsub_rn(im_h, 1.0f);

    x1 = fminf(fmaxf(x1, 0.0f), wmax);
    y1 = fminf(fmaxf(y1, 0.0f), hmax);
    x2 = fminf(fmaxf(x2, 0.0f), wmax);
    y2 = fminf(fmaxf(y2, 0.0f), hmax);

    float min_sz = __fmul_rn(MIN_SIZE_F, sc);
    valid = (__fadd_rn(__fsub_rn(x2, x1), 1.0f) >= min_sz) &&
            (__fadd_rn(__fsub_rn(y2, y1), 1.0f) >= min_sz);
}

// K1: decode + masked score -> sortable key. Pure streaming, no atomics.
__global__ void k_decode(
    const float* __restrict__ scores, const float* __restrict__ deltas,
    const float* __restrict__ im_info, const float* __restrict__ anchors,
    unsigned* __restrict__ keys)
{
    int gt = blockIdx.x * blockDim.x + threadIdx.x;
    if (gt >= B_NUM * N_ANCH) return;
    int pix  = gt & (NPIX - 1);
    int rest = gt >> 14;
    int a = rest % A_NUM;
    int b = rest / A_NUM;
    int idx = pix * A_NUM + a;

    float x1, y1, x2, y2; bool valid;
    decode_box(b, idx, deltas, im_info, anchors, x1, y1, x2, y2, valid);

    float s = scores[((size_t)b * 18 + 9 + a) * NPIX + pix];
    if (!valid) s = NEG_INF_F;
    keys[gt] = sortable_f32(s);
}

// K2: one block per batch. Full 32768-bin histogram in LDS (no global
// atomics), suffix-scan in place, write hist/binbase/thresh/cnt.
__global__ __launch_bounds__(1024) void k_hist_scan(
    const unsigned* __restrict__ keys, unsigned* __restrict__ histg,
    unsigned* __restrict__ binbase, unsigned* __restrict__ cnt,
    unsigned* __restrict__ thresh)
{
    __shared__ unsigned lds[SW(NB2 - 1) + 2];   // 33792 words, swizzled
    __shared__ unsigned csum[1024];
    __shared__ unsigned sT;

    int b = blockIdx.x;
    int t = threadIdx.x;
    if (t == 0) sT = 0;
    for (int i = t; i < SW(NB2 - 1) + 2; i += 1024) lds[i] = 0u;
    __syncthreads();

    // build histogram via LDS atomics
    const unsigned* kb = keys + (size_t)b * N_ANCH;
    for (int i = t; i < N_ANCH; i += 1024)
        atomicAdd(&lds[SW(kb[i] >> 17)], 1u);
    __syncthreads();

    // write hist to global (coalesced)
    unsigned* hg = histg + (size_t)b * NB2;
    for (int i = t; i < NB2; i += 1024) hg[i] = lds[SW(i)];

    // per-thread chunk sum (32 bins, swizzle -> conflict-free)
    int base = t * 32;
    unsigned s = 0;
    for (int u = 0; u < 32; ++u) s += lds[SW(base + u)];
    csum[t] = s;
    __syncthreads();

    // inclusive suffix scan (Hillis-Steele)
    for (int off = 1; off < 1024; off <<= 1) {
        unsigned v = (t + off < 1024) ? csum[t + off] : 0u;
        __syncthreads();
        csum[t] += v;
        __syncthreads();
    }
    unsigned before = csum[t] - s;   // keys in strictly higher chunks

    // find threshold candidate within chunk
    unsigned acc = before;
    for (int bin = base + 31; bin >= base; --bin) {
        unsigned hh = lds[SW(bin)];
        if (acc + hh >= PRE_NMS) { atomicMax(&sT, (unsigned)bin); break; }
        acc += hh;
    }
    __syncthreads();
    unsigned T = sT;

    // walk chunk high->low: overwrite LDS hist with binbase; catch cnt at T
    acc = before;
    for (int bin = base + 31; bin >= base; --bin) {
        unsigned hh = lds[SW(bin)];
        if ((unsigned)bin == T) cnt[b] = acc + hh;
        lds[SW(bin)] = acc;
        acc += hh;
    }
    if (t == 0) thresh[b] = T;
    __syncthreads();

    // write binbase (coalesced)
    unsigned* bb = binbase + (size_t)b * NB2;
    for (int i = t; i < NB2; i += 1024) bb[i] = lds[SW(i)];
}

// K3: scatter passing keys (bin >= T) into bin-segmented array.
__global__ void k_scatter(
    const unsigned* __restrict__ keys, const unsigned* __restrict__ thresh,
    const unsigned* __restrict__ binbase, unsigned* __restrict__ bincnt,
    unsigned long long* __restrict__ seg)
{
    int gt = blockIdx.x * blockDim.x + threadIdx.x;
    int pix  = gt & (NPIX - 1);
    int rest = gt >> 14;
    int a = rest % A_NUM;
    int b = rest / A_NUM;

    unsigned key = keys[gt];
    unsigned bin = key >> 17;
    if (bin >= thresh[b]) {
        unsigned slot = atomicAdd(&bincnt[(size_t)b * NB2 + bin], 1u);
        unsigned pos = binbase[(size_t)b * NB2 + bin] + slot;
        if (pos < SEGCAP) {
            unsigned idx = (unsigned)(pix * A_NUM + a);
            seg[(size_t)b * SEGCAP + pos] =
                ((unsigned long long)key << 32) | (unsigned long long)(0xFFFFFFFFu - idx);
        }
    }
}

// K4: exact rank within own bin segment + binbase = global rank; decode box
// straight into its sorted slot.
__global__ __launch_bounds__(256) void k_rank_decode(
    const unsigned long long* __restrict__ seg, const unsigned* __restrict__ cnt,
    const unsigned* __restrict__ binbase, const unsigned* __restrict__ histg,
    const float* __restrict__ deltas, const float* __restrict__ im_info,
    const float* __restrict__ anchors, float* __restrict__ boxes)
{
    int b = blockIdx.x >> 7;
    int p = ((blockIdx.x & 127) << 8) + threadIdx.x;
    unsigned n = cnt[b];
    if (n > SEGCAP) n = SEGCAP;
    if (p >= (int)n) return;

    const unsigned long long* S = seg + (size_t)b * SEGCAP;
    unsigned long long key = S[p];
    unsigned bin = (unsigned)(key >> 49);
    unsigned base = binbase[(size_t)b * NB2 + bin];
    unsigned end = base + histg[(size_t)b * NB2 + bin];
    if (end > SEGCAP) end = SEGCAP;

    unsigned rank = base;
    for (unsigned q = base; q < end; ++q)
        rank += (S[q] > key) ? 1u : 0u;

    if (rank < PRE_NMS) {
        int idx = (int)(0xFFFFFFFFu - (unsigned)(key & 0xFFFFFFFFull));
        float x1, y1, x2, y2; bool v;
        decode_box(b, idx, deltas, im_info, anchors, x1, y1, x2, y2, v);
        float4 o = make_float4(x1, y1, x2, y2);
        *(float4*)(boxes + ((size_t)b * PRE_NMS + rank) * 4) = o;
    }
}

// One row of a 64x64 suppression block: inter/uni in the reference's exact
// op order; division eliminated except in the proven +-6e-7*uni band
// (round-6 proof; validated absmax=0). Returns the 64-bit suppress mask.
__device__ __forceinline__ unsigned long long iou_row(
    float4 bi, float ia, float jx1, float jy1, float jx2, float jy2, float ja)
{
    float xx1 = fmaxf(bi.x, jx1);
    float yy1 = fmaxf(bi.y, jy1);
    float xx2 = fminf(bi.z, jx2);
    float yy2 = fminf(bi.w, jy2);
    float iw = fmaxf(0.0f, __fadd_rn(__fsub_rn(xx2, xx1), 1.0f));
    float ih = fmaxf(0.0f, __fadd_rn(__fsub_rn(yy2, yy1), 1.0f));
    float inter = __fmul_rn(iw, ih);
    float uni = __fsub_rn(__fadd_rn(ia, ja), inter);
    float diff = __fsub_rn(inter, __fmul_rn(NMS_THRESH_F, uni));
    unsigned long long sup = __ballot(diff > 0.0f);
    unsigned long long band = __ballot(fabsf(diff) <= __fmul_rn(6e-7f, uni));
    if (band) {   // rare; wave-uniform branch
        unsigned long long supd = __ballot(__fdiv_rn(inter, uni) > NMS_THRESH_F);
        sup = (sup & ~band) | (supd & band);
    }
    return sup;
}

// K5a: upper-triangular IoU suppression bitmask, blocked layout
// mask[b][R][C][64] (u64). 256-thread blocks: 4 waves share one row tile
// (LDS loaded once); each wave owns one column PAIR of an 8-column group.
// Full occupancy (8 blocks x 256 = 2048 thr/CU) vs 64-thr blocks' wg-slot
// ceiling. Predicate removal + diagonal scalar mask as in round 8.
__global__ __launch_bounds__(256) void k_iou_mask(
    const float* __restrict__ boxes, unsigned long long* __restrict__ mask)
{
    int bid = blockIdx.x;
    int b = bid / GT_TILES;
    int g = bid - b * GT_TILES;
    int R = 0;
    while (g >= ((RT_TILES - R + 7) >> 3)) { g -= (RT_TILES - R + 7) >> 3; ++R; }

    int wave = threadIdx.x >> 6;
    int lane = threadIdx.x & 63;
    const float* Bb = boxes + (size_t)b * PRE_NMS * 4;

    // row boxes -> LDS (degenerate beyond PRE_NMS); first 64 threads load
    __shared__ float4 rb4[64];
    __shared__ float rba[64];
    if (threadIdx.x < 64) {
        int il = R * 64 + threadIdx.x;
        float4 rv = make_float4(0.f, 0.f, -1.f, -1.f);
        if (il < PRE_NMS) rv = *(const float4*)(Bb + 4 * (size_t)il);
        rb4[threadIdx.x] = rv;
        rba[threadIdx.x] = __fmul_rn(__fadd_rn(__fsub_rn(rv.z, rv.x), 1.0f),
                                     __fadd_rn(__fsub_rn(rv.w, rv.y), 1.0f));
    }
    __syncthreads();

    int C1 = R + g * 8 + wave * 2;
    int C2 = C1 + 1;
    if (C1 >= RT_TILES) return;   // tail waves idle (no barriers below)

    // column boxes (degenerate for j >= PRE_NMS or C out of range)
    float j1x1 = 0.f, j1y1 = 0.f, j1x2 = -1.f, j1y2 = -1.f;
    float j2x1 = 0.f, j2y1 = 0.f, j2x2 = -1.f, j2y2 = -1.f;
    int j1 = C1 * 64 + lane;
    int j2 = C2 * 64 + lane;
    if (j1 < PRE_NMS) {
        float4 v = *(const float4*)(Bb + 4 * (size_t)j1);
        j1x1 = v.x; j1y1 = v.y; j1x2 = v.z; j1y2 = v.w;
    }
    if (C2 < RT_TILES && j2 < PRE_NMS) {
        float4 v = *(const float4*)(Bb + 4 * (size_t)j2);
        j2x1 = v.x; j2y1 = v.y; j2x2 = v.z; j2y2 = v.w;
    }
    float j1a = __fmul_rn(__fadd_rn(__fsub_rn(j1x2, j1x1), 1.0f),
                          __fadd_rn(__fsub_rn(j1y2, j1y1), 1.0f));
    float j2a = __fmul_rn(__fadd_rn(__fsub_rn(j2x2, j2x1), 1.0f),
                          __fadd_rn(__fsub_rn(j2y2, j2y1), 1.0f));

    unsigned long long w1 = 0ULL, w2 = 0ULL;
    if (C1 == R) {   // diagonal tile (g==0, wave==0 only)
        #pragma unroll 4
        for (int ri = 0; ri < 64; ++ri) {
            float4 bi = rb4[ri];
            float ia = rba[ri];
            unsigned long long s1 = iou_row(bi, ia, j1x1, j1y1, j1x2, j1y2, j1a)
                                    & (0xFFFFFFFFFFFFFFFEull << ri);
            unsigned long long s2 = iou_row(bi, ia, j2x1, j2y1, j2x2, j2y2, j2a);
            w1 = (lane == ri) ? s1 : w1;
            w2 = (lane == ri) ? s2 : w2;
        }
    } else {
        #pragma unroll 4
        for (int ri = 0; ri < 64; ++ri) {
            float4 bi = rb4[ri];
            float ia = rba[ri];
            unsigned long long s1 = iou_row(bi, ia, j1x1, j1y1, j1x2, j1y2, j1a);
            unsigned long long s2 = iou_row(bi, ia, j2x1, j2y1, j2x2, j2y2, j2a);
            w1 = (lane == ri) ? s1 : w1;
            w2 = (lane == ri) ? s2 : w2;
        }
    }

    unsigned long long* Mb = mask + (size_t)b * BQWORDS;
    Mb[(size_t)(R * RT_TILES + C1) * 64 + lane] = w1;
    if (C2 < RT_TILES)
        Mb[(size_t)(R * RT_TILES + C2) * 64 + lane] = w2;
}

// K5b: chunked producer-consumer greedy scan. One 256-thread block per
// batch. Row-tile k's mask rows are a CONTIGUOUS 48KB range; waves 1-3
// stream chunk k+1 into an LDS double buffer (coalesced; the pre-barrier
// vmcnt(0) drain guarantees completion) while wave 0 serially resolves
// chunk k's 64 rows from LDS. Garbage C<R qwords only OR bits for already-
// decided j (same argument as before). Rows >= PRE_NMS terminate the scan.
__global__ __launch_bounds__(256) void k_nms_scan(
    const unsigned long long* __restrict__ mask, unsigned* __restrict__ keptbuf)
{
    __shared__ unsigned long long buf[2][64 * SCAN_STRIDE];   // 97,280 B
    __shared__ unsigned long long supp[RT_TILES];
    __shared__ int klist[POST_NMS];
    __shared__ int skept;

    const int b = blockIdx.x;
    const int t = threadIdx.x;
    const unsigned long long* __restrict__ M = mask + (size_t)b * BQWORDS;

    if (t < RT_TILES) supp[t] = 0ULL;
    if (t == 0) skept = 0;

    // prologue: all threads load chunk 0
    for (int q = t; q < CHUNKQ; q += 256) {
        int C = q >> 6, r = q & 63;
        buf[0][r * SCAN_STRIDE + C] = M[q];
    }
    __syncthreads();

    for (int k = 0; k < RT_TILES; ++k) {
        int cur = k & 1;
        if (t >= 64) {
            // waves 1-3: load next chunk
            if (k + 1 < RT_TILES) {
                const unsigned long long* src = M + (size_t)(k + 1) * CHUNKQ;
                for (int q = t - 64; q < CHUNKQ; q += 192) {
                    int C = q >> 6, r = q & 63;
                    buf[cur ^ 1][r * SCAN_STRIDE + C] = src[q];
                }
            }
        } else {
            // wave 0: resolve 64 rows of chunk k
            int lane = t;
            int kcur = skept;
            for (int r = 0; r < 64; ++r) {
                if (kcur >= POST_NMS) break;
                int i = (k << 6) + r;
                if (i >= PRE_NMS) break;
                unsigned long long w = supp[i >> 6];
                if (!((w >> (i & 63)) & 1ULL)) {
                    if (lane == 0) klist[kcur] = i;
                    supp[lane] |= buf[cur][r * SCAN_STRIDE + lane];
                    if (lane < RT_TILES - 64)
                        supp[lane + 64] |= buf[cur][r * SCAN_STRIDE + 64 + lane];
                    ++kcur;
                }
            }
            if (lane == 0) skept = kcur;
        }
        __syncthreads();
    }

    int kept = skept;
    if (t == 0) keptbuf[b * 304] = (unsigned)kept;
    for (int kk = t; kk < POST_NMS; kk += 256)
        keptbuf[b * 304 + 1 + kk] = (kk < kept) ? (unsigned)klist[kk] : 0u;
}

// K5c: write output from kept list.
__global__ void k_nms_gather(const float* __restrict__ boxes,
                             const unsigned* __restrict__ keptbuf,
                             float* __restrict__ out)
{
    int b = blockIdx.x;
    int t = threadIdx.x;
    unsigned kept = keptbuf[b * 304];
    if (t < POST_NMS) {
        size_t o = ((size_t)b * POST_NMS + t) * 5;
        float x1 = 0.f, y1 = 0.f, x2 = 0.f, y2 = 0.f;
        if (t < (int)kept) {
            unsigned idx = keptbuf[b * 304 + 1 + t];
            const float4 v = *(const float4*)(boxes + ((size_t)b * PRE_NMS + idx) * 4);
            x1 = v.x; y1 = v.y; x2 = v.z; y2 = v.w;
        }
        out[o + 0] = (float)b;
        out[o + 1] = x1; out[o + 2] = y1; out[o + 3] = x2; out[o + 4] = y2;
    }
}

// Fallback NMS (used only if ws_size is too small for the bitmask).
__global__ __launch_bounds__(1024) void k_nms_out(
    const float* __restrict__ boxes, float* __restrict__ out)
{
    __shared__ float bx1[PRE_NMS], by1[PRE_NMS], bx2[PRE_NMS], by2[PRE_NMS], bar[PRE_NMS];
    __shared__ unsigned rem[(PRE_NMS + 31) / 32];
    __shared__ int kept_idx[POST_NMS];

    int b = blockIdx.x;
    int t = threadIdx.x;

    for (int p = t; p < PRE_NMS; p += 1024) {
        size_t o = ((size_t)b * PRE_NMS + p) * 4;
        float x1 = boxes[o], y1 = boxes[o + 1], x2 = boxes[o + 2], y2 = boxes[o + 3];
        bx1[p] = x1; by1[p] = y1; bx2[p] = x2; by2[p] = y2;
        bar[p] = __fmul_rn(__fadd_rn(__fsub_rn(x2, x1), 1.0f),
                           __fadd_rn(__fsub_rn(y2, y1), 1.0f));
    }
    for (int p = t; p < (PRE_NMS + 31) / 32; p += 1024) rem[p] = 0u;
    __syncthreads();

    int kept = 0;
    for (int i = 0; i < PRE_NMS && kept < POST_NMS; ++i) {
        if (rem[i >> 5] & (1u << (i & 31))) continue;
        if (t == 0) kept_idx[kept] = i;
        float xi1 = bx1[i], yi1 = by1[i], xi2 = bx2[i], yi2 = by2[i], ai = bar[i];
        for (int j = i + 1 + t; j < PRE_NMS; j += 1024) {
            float xx1 = fmaxf(xi1, bx1[j]);
            float yy1 = fmaxf(yi1, by1[j]);
            float xx2 = fminf(xi2, bx2[j]);
            float yy2 = fminf(yi2, by2[j]);
            float iw = fmaxf(0.0f, __fadd_rn(__fsub_rn(xx2, xx1), 1.0f));
            float ih = fmaxf(0.0f, __fadd_rn(__fsub_rn(yy2, yy1), 1.0f));
            float inter = __fmul_rn(iw, ih);
            if (inter > 0.0f) {
                float uni = __fsub_rn(__fadd_rn(ai, bar[j]), inter);
                float iou = __fdiv_rn(inter, uni);
                if (iou > NMS_THRESH_F) atomicOr(&rem[j >> 5], 1u << (j & 31));
            }
        }
        ++kept;
        __syncthreads();
    }

    for (int k = t; k < POST_NMS; k += 1024) {
        size_t o = ((size_t)b * POST_NMS + k) * 5;
        out[o] = (float)b;
        if (k < kept) {
            int ii = kept_idx[k];
            out[o + 1] = bx1[ii]; out[o + 2] = by1[ii];
            out[o + 3] = bx2[ii]; out[o + 4] = by2[ii];
        } else {
            out[o + 1] = 0.0f; out[o + 2] = 0.0f; out[o + 3] = 0.0f; out[o + 4] = 0.0f;
        }
    }
}

extern "C" void kernel_launch(void* const* d_in, const int* in_sizes, int n_in,
                              void* d_out, int out_size, void* d_ws, size_t ws_size,
                              hipStream_t stream)
{
    const float* scores  = (const float*)d_in[0];
    const float* deltas  = (const float*)d_in[1];
    const float* im_info = (const float*)d_in[2];
    const float* anchors = (const float*)d_in[3];
    float* out = (float*)d_out;
    char* ws = (char*)d_ws;

    unsigned* bincnt           = (unsigned*)(ws + OFF_BINCNT);
    unsigned* cnt              = (unsigned*)(ws + OFF_CNT);
    unsigned* thresh           = cnt + 8;
    unsigned* binbase          = (unsigned*)(ws + OFF_BINBASE);
    unsigned* histg            = (unsigned*)(ws + OFF_HISTG);
    unsigned long long* seg    = (unsigned long long*)(ws + OFF_SEG);
    unsigned* keys             = (unsigned*)(ws + OFF_KEYS);
    float* boxes               = (float*)(ws + OFF_BOXES);
    unsigned* keptbuf          = (unsigned*)(ws + OFF_KEPT);
    unsigned long long* mask   = (unsigned long long*)(ws + OFF_MASK);

    // zero bin counters only
    hipMemsetAsync(ws, 0, OFF_CNT, stream);

    int total = B_NUM * N_ANCH;
    int blk = 256;
    k_decode<<<(total + blk - 1) / blk, blk, 0, stream>>>(
        scores, deltas, im_info, anchors, keys);
    k_hist_scan<<<B_NUM, 1024, 0, stream>>>(keys, histg, binbase, cnt, thresh);
    k_scatter<<<(total + blk - 1) / blk, blk, 0, stream>>>(
        keys, thresh, binbase, bincnt, seg);
    k_rank_decode<<<B_NUM * 128, 256, 0, stream>>>(
        seg, cnt, binbase, histg, deltas, im_info, anchors, boxes);

    if (ws_size >= (size_t)OFF_MASK + MASK_BYTES) {
        k_iou_mask<<<B_NUM * GT_TILES, 256, 0, stream>>>(boxes, mask);
        k_nms_scan<<<B_NUM, 256, 0, stream>>>(mask, keptbuf);
        k_nms_gather<<<B_NUM, 320, 0, stream>>>(boxes, keptbuf, out);
    } else {
        k_nms_out<<<B_NUM, 1024, 0, stream>>>(boxes, out);
    }
}

// Round 10
// 304.164 us; speedup vs baseline: 3.3194x; 3.3194x over previous
//
#include <hip/hip_runtime.h>
#include <stdint.h>

#define FEAT_STRIDE_I 16
#define A_NUM 9
#define HH 128
#define WW 128
#define NPIX (HH * WW)            // 16384
#define N_ANCH (NPIX * A_NUM)     // 147456
#define B_NUM 8
#define PRE_NMS 6000
#define POST_NMS 300
#define NMS_THRESH_F 0.7f
#define MIN_SIZE_F 16.0f
#define NEG_INF_F -1e30f
#define NB2 32768                  // 15-bit bins (key>>17)
#define SEGCAP 16384

#define RT_TILES 94                // ceil(6000/64)
#define GT_TILES 600               // sum_R ceil((94-R)/8): 8-column groups
#define BQWORDS (RT_TILES * RT_TILES * 64)   // 565,504 qwords per batch

// swizzled LDS index: chunk walks (stride 32) become conflict-free
#define SW(i) ((i) + ((i) >> 5))

// ---- workspace layout (bytes) ----
#define OFF_BINCNT  0u             // 8*32768*4 = 1,048,576 (zeroed)
#define OFF_CNT     1048576u       // cnt[8] + thresh[8] (512 B)
#define OFF_BINBASE 1049088u       // 1,048,576
#define OFF_HISTG   2097664u       // 1,048,576
#define OFF_SEG     3146240u       // 8*16384*8 = 1,048,576
#define OFF_KEYS    4194816u       // 8*147456*4 = 4,718,592
#define OFF_BOXES   8913408u       // 8*6000*4*4 = 768,000
#define OFF_KEPT    9681408u       // 8*304*4 = 9,728
#define OFF_MASK    9691136u       // 8*565504*8 = 36,192,256 -> end 45,883,392
#define MASK_BYTES ((size_t)B_NUM * BQWORDS * 8)

__device__ __forceinline__ unsigned sortable_f32(float f) {
    unsigned u = __float_as_uint(f);
    return (u & 0x80000000u) ? ~u : (u | 0x80000000u);
}

// Decode one anchor's box exactly in the reference's op order.
__device__ __forceinline__ void decode_box(
    int b, int idx,
    const float* __restrict__ deltas, const float* __restrict__ im_info,
    const float* __restrict__ anchors,
    float& x1, float& y1, float& x2, float& y2, bool& valid)
{
    int a   = idx % A_NUM;
    int pix = idx / A_NUM;
    int w   = pix & (WW - 1);
    int h   = pix >> 7;

    float a0 = anchors[a * 4 + 0];
    float a1 = anchors[a * 4 + 1];
    float a2 = anchors[a * 4 + 2];
    float a3 = anchors[a * 4 + 3];

    float aw = __fadd_rn(__fsub_rn(a2, a0), 1.0f);
    float ah = __fadd_rn(__fsub_rn(a3, a1), 1.0f);
    float sx = (float)(w * FEAT_STRIDE_I);
    float sy = (float)(h * FEAT_STRIDE_I);
    float acx = __fadd_rn(__fadd_rn(sx, a0), __fmul_rn(0.5f, aw));
    float acy = __fadd_rn(__fadd_rn(sy, a1), __fmul_rn(0.5f, ah));

    size_t base = ((size_t)b * 36 + 4 * a) * NPIX + pix;
    float dx = deltas[base];
    float dy = deltas[base + NPIX];
    float dw = deltas[base + 2 * (size_t)NPIX];
    float dh = deltas[base + 3 * (size_t)NPIX];

    float pcx = __fadd_rn(__fmul_rn(dx, aw), acx);
    float pcy = __fadd_rn(__fmul_rn(dy, ah), acy);
    float pw  = __fmul_rn(expf(dw), aw);
    float ph  = __fmul_rn(expf(dh), ah);

    float hx = __fmul_rn(0.5f, pw);
    float hy = __fmul_rn(0.5f, ph);
    x1 = __fsub_rn(pcx, hx);
    y1 = __fsub_rn(pcy, hy);
    x2 = __fadd_rn(pcx, hx);
    y2 = __fadd_rn(pcy, hy);

    float im_h = im_info[b * 3 + 0];
    float im_w = im_info[b * 3 + 1];
    float sc   = im_info[b * 3 + 2];
    float wmax = __fsub_rn(im_w, 1.0f);
    float hmax = __fsub_rn(im_h, 1.0f);

    x1 = fminf(fmaxf(x1, 0.0f), wmax);
    y1 = fminf(fmaxf(y1, 0.0f), hmax);
    x2 = fminf(fmaxf(x2, 0.0f), wmax);
    y2 = fminf(fmaxf(y2, 0.0f), hmax);

    float min_sz = __fmul_rn(MIN_SIZE_F, sc);
    valid = (__fadd_rn(__fsub_rn(x2, x1), 1.0f) >= min_sz) &&
            (__fadd_rn(__fsub_rn(y2, y1), 1.0f) >= min_sz);
}

// K1: decode + masked score -> sortable key. Pure streaming, no atomics.
__global__ void k_decode(
    const float* __restrict__ scores, const float* __restrict__ deltas,
    const float* __restrict__ im_info, const float* __restrict__ anchors,
    unsigned* __restrict__ keys)
{
    int gt = blockIdx.x * blockDim.x + threadIdx.x;
    if (gt >= B_NUM * N_ANCH) return;
    int pix  = gt & (NPIX - 1);
    int rest = gt >> 14;
    int a = rest % A_NUM;
    int b = rest / A_NUM;
    int idx = pix * A_NUM + a;

    float x1, y1, x2, y2; bool valid;
    decode_box(b, idx, deltas, im_info, anchors, x1, y1, x2, y2, valid);

    float s = scores[((size_t)b * 18 + 9 + a) * NPIX + pix];
    if (!valid) s = NEG_INF_F;
    keys[gt] = sortable_f32(s);
}

// K2: one block per batch. Full 32768-bin histogram in LDS (no global
// atomics), suffix-scan in place, write hist/binbase/thresh/cnt.
__global__ __launch_bounds__(1024) void k_hist_scan(
    const unsigned* __restrict__ keys, unsigned* __restrict__ histg,
    unsigned* __restrict__ binbase, unsigned* __restrict__ cnt,
    unsigned* __restrict__ thresh)
{
    __shared__ unsigned lds[SW(NB2 - 1) + 2];   // 33792 words, swizzled
    __shared__ unsigned csum[1024];
    __shared__ unsigned sT;

    int b = blockIdx.x;
    int t = threadIdx.x;
    if (t == 0) sT = 0;
    for (int i = t; i < SW(NB2 - 1) + 2; i += 1024) lds[i] = 0u;
    __syncthreads();

    // build histogram via LDS atomics
    const unsigned* kb = keys + (size_t)b * N_ANCH;
    for (int i = t; i < N_ANCH; i += 1024)
        atomicAdd(&lds[SW(kb[i] >> 17)], 1u);
    __syncthreads();

    // write hist to global (coalesced)
    unsigned* hg = histg + (size_t)b * NB2;
    for (int i = t; i < NB2; i += 1024) hg[i] = lds[SW(i)];

    // per-thread chunk sum (32 bins, swizzle -> conflict-free)
    int base = t * 32;
    unsigned s = 0;
    for (int u = 0; u < 32; ++u) s += lds[SW(base + u)];
    csum[t] = s;
    __syncthreads();

    // inclusive suffix scan (Hillis-Steele)
    for (int off = 1; off < 1024; off <<= 1) {
        unsigned v = (t + off < 1024) ? csum[t + off] : 0u;
        __syncthreads();
        csum[t] += v;
        __syncthreads();
    }
    unsigned before = csum[t] - s;   // keys in strictly higher chunks

    // find threshold candidate within chunk
    unsigned acc = before;
    for (int bin = base + 31; bin >= base; --bin) {
        unsigned hh = lds[SW(bin)];
        if (acc + hh >= PRE_NMS) { atomicMax(&sT, (unsigned)bin); break; }
        acc += hh;
    }
    __syncthreads();
    unsigned T = sT;

    // walk chunk high->low: overwrite LDS hist with binbase; catch cnt at T
    acc = before;
    for (int bin = base + 31; bin >= base; --bin) {
        unsigned hh = lds[SW(bin)];
        if ((unsigned)bin == T) cnt[b] = acc + hh;
        lds[SW(bin)] = acc;
        acc += hh;
    }
    if (t == 0) thresh[b] = T;
    __syncthreads();

    // write binbase (coalesced)
    unsigned* bb = binbase + (size_t)b * NB2;
    for (int i = t; i < NB2; i += 1024) bb[i] = lds[SW(i)];
}

// K3: scatter passing keys (bin >= T) into bin-segmented array.
__global__ void k_scatter(
    const unsigned* __restrict__ keys, const unsigned* __restrict__ thresh,
    const unsigned* __restrict__ binbase, unsigned* __restrict__ bincnt,
    unsigned long long* __restrict__ seg)
{
    int gt = blockIdx.x * blockDim.x + threadIdx.x;
    int pix  = gt & (NPIX - 1);
    int rest = gt >> 14;
    int a = rest % A_NUM;
    int b = rest / A_NUM;

    unsigned key = keys[gt];
    unsigned bin = key >> 17;
    if (bin >= thresh[b]) {
        unsigned slot = atomicAdd(&bincnt[(size_t)b * NB2 + bin], 1u);
        unsigned pos = binbase[(size_t)b * NB2 + bin] + slot;
        if (pos < SEGCAP) {
            unsigned idx = (unsigned)(pix * A_NUM + a);
            seg[(size_t)b * SEGCAP + pos] =
                ((unsigned long long)key << 32) | (unsigned long long)(0xFFFFFFFFu - idx);
        }
    }
}

// K4: exact rank within own bin segment + binbase = global rank; decode box
// straight into its sorted slot.
__global__ __launch_bounds__(256) void k_rank_decode(
    const unsigned long long* __restrict__ seg, const unsigned* __restrict__ cnt,
    const unsigned* __restrict__ binbase, const unsigned* __restrict__ histg,
    const float* __restrict__ deltas, const float* __restrict__ im_info,
    const float* __restrict__ anchors, float* __restrict__ boxes)
{
    int b = blockIdx.x >> 7;
    int p = ((blockIdx.x & 127) << 8) + threadIdx.x;
    unsigned n = cnt[b];
    if (n > SEGCAP) n = SEGCAP;
    if (p >= (int)n) return;

    const unsigned long long* S = seg + (size_t)b * SEGCAP;
    unsigned long long key = S[p];
    unsigned bin = (unsigned)(key >> 49);
    unsigned base = binbase[(size_t)b * NB2 + bin];
    unsigned end = base + histg[(size_t)b * NB2 + bin];
    if (end > SEGCAP) end = SEGCAP;

    unsigned rank = base;
    for (unsigned q = base; q < end; ++q)
        rank += (S[q] > key) ? 1u : 0u;

    if (rank < PRE_NMS) {
        int idx = (int)(0xFFFFFFFFu - (unsigned)(key & 0xFFFFFFFFull));
        float x1, y1, x2, y2; bool v;
        decode_box(b, idx, deltas, im_info, anchors, x1, y1, x2, y2, v);
        float4 o = make_float4(x1, y1, x2, y2);
        *(float4*)(boxes + ((size_t)b * PRE_NMS + rank) * 4) = o;
    }
}

// One row of a 64x64 suppression block: inter/uni in the reference's exact
// op order; division eliminated except in the proven +-6e-7*uni band
// (round-6 proof; validated absmax=0). Returns the 64-bit suppress mask.
__device__ __forceinline__ unsigned long long iou_row(
    float4 bi, float ia, float jx1, float jy1, float jx2, float jy2, float ja)
{
    float xx1 = fmaxf(bi.x, jx1);
    float yy1 = fmaxf(bi.y, jy1);
    float xx2 = fminf(bi.z, jx2);
    float yy2 = fminf(bi.w, jy2);
    float iw = fmaxf(0.0f, __fadd_rn(__fsub_rn(xx2, xx1), 1.0f));
    float ih = fmaxf(0.0f, __fadd_rn(__fsub_rn(yy2, yy1), 1.0f));
    float inter = __fmul_rn(iw, ih);
    float uni = __fsub_rn(__fadd_rn(ia, ja), inter);
    float diff = __fsub_rn(inter, __fmul_rn(NMS_THRESH_F, uni));
    unsigned long long sup = __ballot(diff > 0.0f);
    unsigned long long band = __ballot(fabsf(diff) <= __fmul_rn(6e-7f, uni));
    if (band) {   // rare; wave-uniform branch
        unsigned long long supd = __ballot(__fdiv_rn(inter, uni) > NMS_THRESH_F);
        sup = (sup & ~band) | (supd & band);
    }
    return sup;
}

// K5a: upper-triangular IoU suppression bitmask, blocked layout
// mask[b][R][C][64] (u64). 256-thread blocks: 4 waves share one row tile
// (LDS loaded once); each wave owns one column PAIR of an 8-column group.
__global__ __launch_bounds__(256) void k_iou_mask(
    const float* __restrict__ boxes, unsigned long long* __restrict__ mask)
{
    int bid = blockIdx.x;
    int b = bid / GT_TILES;
    int g = bid - b * GT_TILES;
    int R = 0;
    while (g >= ((RT_TILES - R + 7) >> 3)) { g -= (RT_TILES - R + 7) >> 3; ++R; }

    int wave = threadIdx.x >> 6;
    int lane = threadIdx.x & 63;
    const float* Bb = boxes + (size_t)b * PRE_NMS * 4;

    // row boxes -> LDS (degenerate beyond PRE_NMS); first 64 threads load
    __shared__ float4 rb4[64];
    __shared__ float rba[64];
    if (threadIdx.x < 64) {
        int il = R * 64 + threadIdx.x;
        float4 rv = make_float4(0.f, 0.f, -1.f, -1.f);
        if (il < PRE_NMS) rv = *(const float4*)(Bb + 4 * (size_t)il);
        rb4[threadIdx.x] = rv;
        rba[threadIdx.x] = __fmul_rn(__fadd_rn(__fsub_rn(rv.z, rv.x), 1.0f),
                                     __fadd_rn(__fsub_rn(rv.w, rv.y), 1.0f));
    }
    __syncthreads();

    int C1 = R + g * 8 + wave * 2;
    int C2 = C1 + 1;
    if (C1 >= RT_TILES) return;   // tail waves idle (no barriers below)

    // column boxes (degenerate for j >= PRE_NMS or C out of range)
    float j1x1 = 0.f, j1y1 = 0.f, j1x2 = -1.f, j1y2 = -1.f;
    float j2x1 = 0.f, j2y1 = 0.f, j2x2 = -1.f, j2y2 = -1.f;
    int j1 = C1 * 64 + lane;
    int j2 = C2 * 64 + lane;
    if (j1 < PRE_NMS) {
        float4 v = *(const float4*)(Bb + 4 * (size_t)j1);
        j1x1 = v.x; j1y1 = v.y; j1x2 = v.z; j1y2 = v.w;
    }
    if (C2 < RT_TILES && j2 < PRE_NMS) {
        float4 v = *(const float4*)(Bb + 4 * (size_t)j2);
        j2x1 = v.x; j2y1 = v.y; j2x2 = v.z; j2y2 = v.w;
    }
    float j1a = __fmul_rn(__fadd_rn(__fsub_rn(j1x2, j1x1), 1.0f),
                          __fadd_rn(__fsub_rn(j1y2, j1y1), 1.0f));
    float j2a = __fmul_rn(__fadd_rn(__fsub_rn(j2x2, j2x1), 1.0f),
                          __fadd_rn(__fsub_rn(j2y2, j2y1), 1.0f));

    unsigned long long w1 = 0ULL, w2 = 0ULL;
    if (C1 == R) {   // diagonal tile (g==0, wave==0 only)
        #pragma unroll 4
        for (int ri = 0; ri < 64; ++ri) {
            float4 bi = rb4[ri];
            float ia = rba[ri];
            unsigned long long s1 = iou_row(bi, ia, j1x1, j1y1, j1x2, j1y2, j1a)
                                    & (0xFFFFFFFFFFFFFFFEull << ri);
            unsigned long long s2 = iou_row(bi, ia, j2x1, j2y1, j2x2, j2y2, j2a);
            w1 = (lane == ri) ? s1 : w1;
            w2 = (lane == ri) ? s2 : w2;
        }
    } else {
        #pragma unroll 4
        for (int ri = 0; ri < 64; ++ri) {
            float4 bi = rb4[ri];
            float ia = rba[ri];
            unsigned long long s1 = iou_row(bi, ia, j1x1, j1y1, j1x2, j1y2, j1a);
            unsigned long long s2 = iou_row(bi, ia, j2x1, j2y1, j2x2, j2y2, j2a);
            w1 = (lane == ri) ? s1 : w1;
            w2 = (lane == ri) ? s2 : w2;
        }
    }

    unsigned long long* Mb = mask + (size_t)b * BQWORDS;
    Mb[(size_t)(R * RT_TILES + C1) * 64 + lane] = w1;
    if (C2 < RT_TILES)
        Mb[(size_t)(R * RT_TILES + C2) * 64 + lane] = w2;
}

// K5b: serial greedy scan over the blocked bitmask, one wave per batch.
// Row i's 94 qwords live at M[(R*94+C)*64 + r], C = 0..93 (stride 512B).
// Lane l covers C=l and (l<30) C=64+l. 8-deep unconditional prefetch:
// 8 adjacent rows share each 64B line -> full L1 reuse, latency/8 per row.
// (Round-9's LDS producer-consumer variant regressed 8x: dependent
// load->LDS chains + per-chunk barriers collapsed the pipeline. Reverted.)
__global__ __launch_bounds__(64) void k_nms_scan(
    const unsigned long long* __restrict__ mask, unsigned* __restrict__ keptbuf)
{
    const int b = blockIdx.x;
    const int l = threadIdx.x;
    __shared__ unsigned long long supp[RT_TILES];
    __shared__ int klist[POST_NMS];
    supp[l] = 0ULL;
    if (l < RT_TILES - 64) supp[l + 64] = 0ULL;
    __syncthreads();

    const unsigned long long* __restrict__ M = mask + (size_t)b * BQWORDS;
    int kept = 0;
    unsigned long long curw = 0; int curwi = -1;

#define LOADROW(p0, p1, i) { \
        int _i = ((i) < PRE_NMS) ? (i) : (PRE_NMS - 1); \
        const unsigned long long* _r = M + (size_t)((_i >> 6) * RT_TILES) * 64 + (_i & 63); \
        p0 = _r[l * 64]; \
        p1 = (l < RT_TILES - 64) ? _r[(64 + l) * 64] : 0ULL; }

#define STEP(i, p0, p1) { \
        if (kept < POST_NMS) { \
            int _wi = (i) >> 6; \
            if (_wi != curwi) { curw = supp[_wi]; curwi = _wi; } \
            if (!((curw >> ((i) & 63)) & 1ULL)) { \
                if (l == 0) klist[kept] = (i); \
                supp[l] |= p0; \
                if (l < RT_TILES - 64) supp[l + 64] |= p1; \
                ++kept; curwi = -1; \
            } \
        } }

    unsigned long long a0, a1, c0, c1, d0, d1, e0, e1;
    unsigned long long f0, f1, g0, g1, h0, h1, q0, q1;
    LOADROW(a0, a1, 0) LOADROW(c0, c1, 1)
    LOADROW(d0, d1, 2) LOADROW(e0, e1, 3)
    LOADROW(f0, f1, 4) LOADROW(g0, g1, 5)
    LOADROW(h0, h1, 6) LOADROW(q0, q1, 7)

    for (int i = 0; i < PRE_NMS && kept < POST_NMS; i += 8) {
        STEP(i + 0, a0, a1) LOADROW(a0, a1, i + 8)
        STEP(i + 1, c0, c1) LOADROW(c0, c1, i + 9)
        STEP(i + 2, d0, d1) LOADROW(d0, d1, i + 10)
        STEP(i + 3, e0, e1) LOADROW(e0, e1, i + 11)
        STEP(i + 4, f0, f1) LOADROW(f0, f1, i + 12)
        STEP(i + 5, g0, g1) LOADROW(g0, g1, i + 13)
        STEP(i + 6, h0, h1) LOADROW(h0, h1, i + 14)
        STEP(i + 7, q0, q1) LOADROW(q0, q1, i + 15)
    }
    __syncthreads();
    if (l == 0) keptbuf[b * 304] = (unsigned)kept;
    for (int k = l; k < POST_NMS; k += 64)
        keptbuf[b * 304 + 1 + k] = (k < (int)kept) ? (unsigned)klist[k] : 0u;
#undef LOADROW
#undef STEP
}

// K5c: write output from kept list.
__global__ void k_nms_gather(const float* __restrict__ boxes,
                             const unsigned* __restrict__ keptbuf,
                             float* __restrict__ out)
{
    int b = blockIdx.x;
    int t = threadIdx.x;
    unsigned kept = keptbuf[b * 304];
    if (t < POST_NMS) {
        size_t o = ((size_t)b * POST_NMS + t) * 5;
        float x1 = 0.f, y1 = 0.f, x2 = 0.f, y2 = 0.f;
        if (t < (int)kept) {
            unsigned idx = keptbuf[b * 304 + 1 + t];
            const float4 v = *(const float4*)(boxes + ((size_t)b * PRE_NMS + idx) * 4);
            x1 = v.x; y1 = v.y; x2 = v.z; y2 = v.w;
        }
        out[o + 0] = (float)b;
        out[o + 1] = x1; out[o + 2] = y1; out[o + 3] = x2; out[o + 4] = y2;
    }
}

// Fallback NMS (used only if ws_size is too small for the bitmask).
__global__ __launch_bounds__(1024) void k_nms_out(
    const float* __restrict__ boxes, float* __restrict__ out)
{
    __shared__ float bx1[PRE_NMS], by1[PRE_NMS], bx2[PRE_NMS], by2[PRE_NMS], bar[PRE_NMS];
    __shared__ unsigned rem[(PRE_NMS + 31) / 32];
    __shared__ int kept_idx[POST_NMS];

    int b = blockIdx.x;
    int t = threadIdx.x;

    for (int p = t; p < PRE_NMS; p += 1024) {
        size_t o = ((size_t)b * PRE_NMS + p) * 4;
        float x1 = boxes[o], y1 = boxes[o + 1], x2 = boxes[o + 2], y2 = boxes[o + 3];
        bx1[p] = x1; by1[p] = y1; bx2[p] = x2; by2[p] = y2;
        bar[p] = __fmul_rn(__fadd_rn(__fsub_rn(x2, x1), 1.0f),
                           __fadd_rn(__fsub_rn(y2, y1), 1.0f));
    }
    for (int p = t; p < (PRE_NMS + 31) / 32; p += 1024) rem[p] = 0u;
    __syncthreads();

    int kept = 0;
    for (int i = 0; i < PRE_NMS && kept < POST_NMS; ++i) {
        if (rem[i >> 5] & (1u << (i & 31))) continue;
        if (t == 0) kept_idx[kept] = i;
        float xi1 = bx1[i], yi1 = by1[i], xi2 = bx2[i], yi2 = by2[i], ai = bar[i];
        for (int j = i + 1 + t; j < PRE_NMS; j += 1024) {
            float xx1 = fmaxf(xi1, bx1[j]);
            float yy1 = fmaxf(yi1, by1[j]);
            float xx2 = fminf(xi2, bx2[j]);
            float yy2 = fminf(yi2, by2[j]);
            float iw = fmaxf(0.0f, __fadd_rn(__fsub_rn(xx2, xx1), 1.0f));
            float ih = fmaxf(0.0f, __fadd_rn(__fsub_rn(yy2, yy1), 1.0f));
            float inter = __fmul_rn(iw, ih);
            if (inter > 0.0f) {
                float uni = __fsub_rn(__fadd_rn(ai, bar[j]), inter);
                float iou = __fdiv_rn(inter, uni);
                if (iou > NMS_THRESH_F) atomicOr(&rem[j >> 5], 1u << (j & 31));
            }
        }
        ++kept;
        __syncthreads();
    }

    for (int k = t; k < POST_NMS; k += 1024) {
        size_t o = ((size_t)b * POST_NMS + k) * 5;
        out[o] = (float)b;
        if (k < kept) {
            int ii = kept_idx[k];
            out[o + 1] = bx1[ii]; out[o + 2] = by1[ii];
            out[o + 3] = bx2[ii]; out[o + 4] = by2[ii];
        } else {
            out[o + 1] = 0.0f; out[o + 2] = 0.0f; out[o + 3] = 0.0f; out[o + 4] = 0.0f;
        }
    }
}

extern "C" void kernel_launch(void* const* d_in, const int* in_sizes, int n_in,
                              void* d_out, int out_size, void* d_ws, size_t ws_size,
                              hipStream_t stream)
{
    const float* scores  = (const float*)d_in[0];
    const float* deltas  = (const float*)d_in[1];
    const float* im_info = (const float*)d_in[2];
    const float* anchors = (const float*)d_in[3];
    float* out = (float*)d_out;
    char* ws = (char*)d_ws;

    unsigned* bincnt           = (unsigned*)(ws + OFF_BINCNT);
    unsigned* cnt              = (unsigned*)(ws + OFF_CNT);
    unsigned* thresh           = cnt + 8;
    unsigned* binbase          = (unsigned*)(ws + OFF_BINBASE);
    unsigned* histg            = (unsigned*)(ws + OFF_HISTG);
    unsigned long long* seg    = (unsigned long long*)(ws + OFF_SEG);
    unsigned* keys             = (unsigned*)(ws + OFF_KEYS);
    float* boxes               = (float*)(ws + OFF_BOXES);
    unsigned* keptbuf          = (unsigned*)(ws + OFF_KEPT);
    unsigned long long* mask   = (unsigned long long*)(ws + OFF_MASK);

    // zero bin counters only
    hipMemsetAsync(ws, 0, OFF_CNT, stream);

    int total = B_NUM * N_ANCH;
    int blk = 256;
    k_decode<<<(total + blk - 1) / blk, blk, 0, stream>>>(
        scores, deltas, im_info, anchors, keys);
    k_hist_scan<<<B_NUM, 1024, 0, stream>>>(keys, histg, binbase, cnt, thresh);
    k_scatter<<<(total + blk - 1) / blk, blk, 0, stream>>>(
        keys, thresh, binbase, bincnt, seg);
    k_rank_decode<<<B_NUM * 128, 256, 0, stream>>>(
        seg, cnt, binbase, histg, deltas, im_info, anchors, boxes);

    if (ws_size >= (size_t)OFF_MASK + MASK_BYTES) {
        k_iou_mask<<<B_NUM * GT_TILES, 256, 0, stream>>>(boxes, mask);
        k_nms_scan<<<B_NUM, 64, 0, stream>>>(mask, keptbuf);
        k_nms_gather<<<B_NUM, 320, 0, stream>>>(boxes, keptbuf, out);
    } else {
        k_nms_out<<<B_NUM, 1024, 0, stream>>>(boxes, out);
    }
}